// Round 13
// baseline (72.890 us; speedup 1.0000x reference)
//
#include <hip/hip_runtime.h>

#define NEG_SLOPE 0.1f

__device__ __forceinline__ float leaky(float v) { return v > 0.0f ? v : NEG_SLOPE * v; }

typedef _Float16 h4_t __attribute__((ext_vector_type(4)));
typedef _Float16 h8_t __attribute__((ext_vector_type(8)));
typedef float f32x4 __attribute__((ext_vector_type(4)));

__device__ __forceinline__ unsigned lds_off(const void* p) {
    return (unsigned)(unsigned long long)p;
}

__device__ __forceinline__ void lgkm0() {
    asm volatile("s_waitcnt lgkmcnt(0)" ::: "memory");
    __builtin_amdgcn_sched_barrier(0);        // rule #18
}

__device__ __forceinline__ h4_t tr16(unsigned addr) {
    h4_t d;
    asm volatile("ds_read_b64_tr_b16 %0, %1" : "=v"(d) : "v"(addr) : "memory");
    return d;
}

// ---------------------------------------------------------------------------
// K0: merged PREP (W2T + W1T + wpack, R11 K=32 B-frag pack) || split-K GEMM.
// blocks [0,1024): W2T; [1024,1088): W1T; [1088,3392): pack;
// blocks [3392,4416): splitk for t-partials (R11 logic, remapped ids).
// ---------------------------------------------------------------------------
__global__ __launch_bounds__(256) void prep_and_splitk(const float* __restrict__ W2,
                                                       const float* __restrict__ W1,
                                                       const float* __restrict__ a1W,
                                                       const float* __restrict__ a2W,
                                                       const float* __restrict__ Wp2,
                                                       const float* __restrict__ x,
                                                       const float* __restrict__ Wpca,
                                                       _Float16* __restrict__ W2T,
                                                       _Float16* __restrict__ W1T,
                                                       _Float16* __restrict__ wpack,
                                                       float* __restrict__ P)
{
    __shared__ float tile[32][33];
    __shared__ alignas(16) float As[32][33];
    __shared__ alignas(16) float Bs[32][64];
    const int b   = blockIdx.x;
    const int tid = threadIdx.x;

    if (b < 1024) {                         // W2T[n][k] = fp16 W2[k][n]
        const int n0 = (b & 31) * 32, k0 = (b >> 5) * 32;
        const int r = tid >> 3, c4 = (tid & 7) * 4;
        float4 v = *reinterpret_cast<const float4*>(&W2[(size_t)(k0 + r) * 1024 + n0 + c4]);
        tile[r][c4 + 0] = v.x; tile[r][c4 + 1] = v.y;
        tile[r][c4 + 2] = v.z; tile[r][c4 + 3] = v.w;
        __syncthreads();
        h4_t o;
        o[0] = (_Float16)tile[c4 + 0][r]; o[1] = (_Float16)tile[c4 + 1][r];
        o[2] = (_Float16)tile[c4 + 2][r]; o[3] = (_Float16)tile[c4 + 3][r];
        *reinterpret_cast<h4_t*>(&W2T[(size_t)(n0 + r) * 1024 + k0 + c4]) = o;
    } else if (b < 1088) {                  // W1T[n][k] = fp16 W1[k][n]  (k<64)
        const int b2 = b - 1024;
        const int n0 = (b2 & 31) * 32, k0 = (b2 >> 5) * 32;
        const int r = tid >> 3, c4 = (tid & 7) * 4;
        float4 v = *reinterpret_cast<const float4*>(&W1[(size_t)(k0 + r) * 1024 + n0 + c4]);
        tile[r][c4 + 0] = v.x; tile[r][c4 + 1] = v.y;
        tile[r][c4 + 2] = v.z; tile[r][c4 + 3] = v.w;
        __syncthreads();
        h4_t o;
        o[0] = (_Float16)tile[c4 + 0][r]; o[1] = (_Float16)tile[c4 + 1][r];
        o[2] = (_Float16)tile[c4 + 2][r]; o[3] = (_Float16)tile[c4 + 3][r];
        *reinterpret_cast<h4_t*>(&W1T[(size_t)(n0 + r) * 64 + k0 + c4]) = o;
    } else if (b < 3392) {                  // pack tail weights (K=32 B-frag, R11)
        const int idx = (b - 1088) * 256 + tid;   // < 589824
        if (idx < 589824) {
            const int r = idx / 9216, qq = idx % 9216;
            float v;
            if (qq < 1024) {
                int nt = qq >> 8, rem = qq & 255, l = rem >> 2, j = rem & 3;
                int n = nt * 16 + (l & 15), k = (l >> 4) * 4 + j;
                v = a1W[(size_t)r * 1024 + k * 64 + n];
            } else if (qq < 5120) {
                int p = qq - 1024, kt = p >> 11, u = p & 2047, nt = u >> 9, s = u & 511,
                    l = s >> 3, j = s & 7;
                int n = nt * 16 + (l & 15), k = kt * 32 + (l >> 4) * 8 + j;
                v = a2W[(size_t)r * 4096 + k * 64 + n];
            } else {
                int p = qq - 5120, kt = p >> 11, u = p & 2047, nt = u >> 9, s = u & 511,
                    l = s >> 3, j = s & 7;
                int n = nt * 16 + (l & 15), k = kt * 32 + (l >> 4) * 8 + j;
                v = Wp2[((size_t)r * 64 + k) * 64 + n];
            }
            wpack[idx] = (_Float16)v;
        }
    } else {                                // split-K: t partials [8][4096][64]
        const int b2    = b - 3392;
        const int row0  = (b2 & 127) * 32;
        const int kbase = (b2 >> 7) * 128;
        const int r0    = (tid >> 4) * 2;
        const int c0    = (tid & 15) * 4;
        const int am    = tid >> 3;
        const int ak    = (tid & 7) * 4;
        float acc[2][4] = {};

#pragma unroll
        for (int kc = 0; kc < 128; kc += 32) {
            const int k0 = kbase + kc;
            float4 va = *reinterpret_cast<const float4*>(&x[(size_t)(row0 + am) * 1024 + k0 + ak]);
            As[ak + 0][am] = va.x; As[ak + 1][am] = va.y;
            As[ak + 2][am] = va.z; As[ak + 3][am] = va.w;
#pragma unroll
            for (int p = 0; p < 2; ++p) {
                int idx = tid + p * 256;
                int kk  = idx >> 4;
                int nq  = (idx & 15) * 4;
                *reinterpret_cast<float4*>(&Bs[kk][nq]) =
                    *reinterpret_cast<const float4*>(&Wpca[(size_t)(k0 + kk) * 64 + nq]);
            }
            __syncthreads();
#pragma unroll
            for (int k = 0; k < 32; ++k) {
                float a0 = As[k][r0], a1 = As[k][r0 + 1];
                float4 bv = *reinterpret_cast<const float4*>(&Bs[k][c0]);
                acc[0][0] = fmaf(a0, bv.x, acc[0][0]); acc[0][1] = fmaf(a0, bv.y, acc[0][1]);
                acc[0][2] = fmaf(a0, bv.z, acc[0][2]); acc[0][3] = fmaf(a0, bv.w, acc[0][3]);
                acc[1][0] = fmaf(a1, bv.x, acc[1][0]); acc[1][1] = fmaf(a1, bv.y, acc[1][1]);
                acc[1][2] = fmaf(a1, bv.z, acc[1][2]); acc[1][3] = fmaf(a1, bv.w, acc[1][3]);
            }
            __syncthreads();
        }
#pragma unroll
        for (int i = 0; i < 2; ++i) {
            float4 o; o.x = acc[i][0]; o.y = acc[i][1]; o.z = acc[i][2]; o.w = acc[i][3];
            *reinterpret_cast<float4*>(
                &P[((size_t)(b2 >> 7) * 4096 + row0 + r0 + i) * 64 + c0]) = o;
        }
    }
}

// ---------------------------------------------------------------------------
// K2': h1 = leaky(t @ W1 + b1) via fp16 MFMA (K=64), with the t-combine
// FUSED: A-tile reg-staged as sum of 8 splitk partials + bpca (identical
// summation order to the old combine_t16), fp16-converted, ds_write to the
// same linear LDS address global_load_lds used. B staging unchanged.
// ---------------------------------------------------------------------------
__global__ __launch_bounds__(256) void gemm_k64_mfma_fused(const float* __restrict__ tpart,
                                                           const float* __restrict__ bpca,
                                                           const _Float16* __restrict__ BT,
                                                           const float* __restrict__ bias,
                                                           _Float16* __restrict__ C)
{
    __shared__ alignas(16) _Float16 As[128 * 64];
    __shared__ alignas(16) _Float16 Bs[128 * 64];
    const int tid = threadIdx.x;
    const int l   = tid & 63;
    const int w   = tid >> 6;
    const int wm  = w >> 1;
    const int wn  = w & 1;
    const int bm0 = blockIdx.y * 128;
    const int bn0 = blockIdx.x * 128;
    const int fr  = l & 15;
    const int fg  = l >> 4;
    const int srow  = l >> 3;
    const int sslot = l & 7;

#pragma unroll
    for (int i = 0; i < 4; ++i) {
        const int r0   = w * 32 + i * 8;
        const int rowA = r0 + srow;
        const int slot = sslot ^ (rowA & 7);
        // ---- A: combine 8 partials + bias -> fp16, write linear LDS (l*8)
        const size_t base = (size_t)(bm0 + rowA) * 64 + slot * 8;
        float4 s0 = *reinterpret_cast<const float4*>(&bpca[slot * 8]);
        float4 s1 = *reinterpret_cast<const float4*>(&bpca[slot * 8 + 4]);
#pragma unroll
        for (int ch = 0; ch < 8; ++ch) {
            float4 p0 = *reinterpret_cast<const float4*>(&tpart[(size_t)ch * 262144 + base]);
            float4 p1 = *reinterpret_cast<const float4*>(&tpart[(size_t)ch * 262144 + base + 4]);
            s0.x += p0.x; s0.y += p0.y; s0.z += p0.z; s0.w += p0.w;
            s1.x += p1.x; s1.y += p1.y; s1.z += p1.z; s1.w += p1.w;
        }
        h8_t av;
        av[0] = (_Float16)s0.x; av[1] = (_Float16)s0.y;
        av[2] = (_Float16)s0.z; av[3] = (_Float16)s0.w;
        av[4] = (_Float16)s1.x; av[5] = (_Float16)s1.y;
        av[6] = (_Float16)s1.z; av[7] = (_Float16)s1.w;
        *reinterpret_cast<h8_t*>(&As[r0 * 64 + l * 8]) = av;
        // ---- B: unchanged global_load_lds staging
        __builtin_amdgcn_global_load_lds(
            (const __attribute__((address_space(1))) void*)&BT[(size_t)(bn0 + rowA) * 64 + slot * 8],
            (__attribute__((address_space(3))) void*)&Bs[r0 * 64], 16, 0, 0);
    }
    __syncthreads();

    f32x4 acc[4][4] = {};
#pragma unroll
    for (int ks = 0; ks < 2; ++ks) {
        h8_t af[4], bf[4];
#pragma unroll
        for (int mt = 0; mt < 4; ++mt) {
            int row = wm * 64 + mt * 16 + fr;
            int sg  = ks * 4 + fg;
            af[mt] = *reinterpret_cast<const h8_t*>(&As[row * 64 + ((sg ^ (row & 7)) << 3)]);
        }
#pragma unroll
        for (int nt = 0; nt < 4; ++nt) {
            int row = wn * 64 + nt * 16 + fr;
            int sg  = ks * 4 + fg;
            bf[nt] = *reinterpret_cast<const h8_t*>(&Bs[row * 64 + ((sg ^ (row & 7)) << 3)]);
        }
#pragma unroll
        for (int mt = 0; mt < 4; ++mt)
#pragma unroll
            for (int nt = 0; nt < 4; ++nt)
                acc[mt][nt] = __builtin_amdgcn_mfma_f32_16x16x32_f16(af[mt], bf[nt],
                                                                     acc[mt][nt], 0, 0, 0);
    }

#pragma unroll
    for (int nt = 0; nt < 4; ++nt) {
        const int col = bn0 + wn * 64 + nt * 16 + fr;
        const float bv = bias[col];
#pragma unroll
        for (int mt = 0; mt < 4; ++mt)
#pragma unroll
            for (int rg = 0; rg < 4; ++rg) {
                const int row = bm0 + wm * 64 + mt * 16 + fg * 4 + rg;
                float v = acc[mt][nt][rg] + bv;
                C[(size_t)row * 1024 + col] = (_Float16)fmaxf(v, NEG_SLOPE * v);
            }
    }
}

// ---------------------------------------------------------------------------
// K3 v2: h2t = pack(leaky(h1 @ W2 + b2)). (unchanged from round 11)
// ---------------------------------------------------------------------------
__global__ __launch_bounds__(256) void gemm_mfma_f16_v2(const _Float16* __restrict__ A,
                                                        const _Float16* __restrict__ BT,
                                                        const float* __restrict__ bias,
                                                        _Float16* __restrict__ h2t)
{
    __shared__ alignas(16) _Float16 As[64 * 64];
    __shared__ alignas(16) _Float16 Bs[128 * 64];
    const int tid = threadIdx.x;
    const int l   = tid & 63;
    const int w   = tid >> 6;
    const int wm  = w >> 1;
    const int wn  = w & 1;
    const int bm0 = blockIdx.y * 64;
    const int bn0 = blockIdx.x * 128;
    const int fr  = l & 15;
    const int fg  = l >> 4;
    const int srow  = l >> 3;
    const int sslot = l & 7;

    f32x4 acc[2][4] = {};

    for (int k0 = 0; k0 < 1024; k0 += 64) {
#pragma unroll
        for (int i = 0; i < 2; ++i) {
            const int r0   = w * 16 + i * 8;
            const int rowA = r0 + srow;
            const int slot = sslot ^ (rowA & 7);
            __builtin_amdgcn_global_load_lds(
                (const __attribute__((address_space(1))) void*)&A[(size_t)(bm0 + rowA) * 1024 + k0 + slot * 8],
                (__attribute__((address_space(3))) void*)&As[r0 * 64], 16, 0, 0);
        }
#pragma unroll
        for (int i = 0; i < 4; ++i) {
            const int r0   = w * 32 + i * 8;
            const int rowB = r0 + srow;
            const int slot = sslot ^ (rowB & 7);
            __builtin_amdgcn_global_load_lds(
                (const __attribute__((address_space(1))) void*)&BT[(size_t)(bn0 + rowB) * 1024 + k0 + slot * 8],
                (__attribute__((address_space(3))) void*)&Bs[r0 * 64], 16, 0, 0);
        }
        __syncthreads();

#pragma unroll
        for (int ks = 0; ks < 2; ++ks) {
            h8_t af[2], bf[4];
#pragma unroll
            for (int mt = 0; mt < 2; ++mt) {
                int row = wm * 32 + mt * 16 + fr;
                int sg  = ks * 4 + fg;
                af[mt] = *reinterpret_cast<const h8_t*>(&As[row * 64 + ((sg ^ (row & 7)) << 3)]);
            }
#pragma unroll
            for (int nt = 0; nt < 4; ++nt) {
                int row = wn * 64 + nt * 16 + fr;
                int sg  = ks * 4 + fg;
                bf[nt] = *reinterpret_cast<const h8_t*>(&Bs[row * 64 + ((sg ^ (row & 7)) << 3)]);
            }
#pragma unroll
            for (int mt = 0; mt < 2; ++mt)
#pragma unroll
                for (int nt = 0; nt < 4; ++nt)
                    acc[mt][nt] = __builtin_amdgcn_mfma_f32_16x16x32_f16(af[mt], bf[nt],
                                                                         acc[mt][nt], 0, 0, 0);
        }
        __syncthreads();
    }

    const int rblk0 = (bm0 >> 4) + wm * 2;
    const int cblk0 = (bn0 >> 4) + wn * 4;
#pragma unroll
    for (int nt = 0; nt < 4; ++nt) {
        const int col = bn0 + wn * 64 + nt * 16 + fr;
        const float bv = bias[col];
#pragma unroll
        for (int mt = 0; mt < 2; ++mt) {
            h4_t pk;
#pragma unroll
            for (int r = 0; r < 4; ++r) {
                float v = acc[mt][nt][r] + bv;
                pk[r] = (_Float16)fmaxf(v, NEG_SLOPE * v);
            }
            *reinterpret_cast<h4_t*>(
                &h2t[(((size_t)(cblk0 + nt) * 256 + rblk0 + mt) * 16 + fr) * 16 + fg * 4]) = pk;
        }
    }
}

// ---------------------------------------------------------------------------
// K4: fused additive chain v5 (byte-identical to passing round 11).
// ---------------------------------------------------------------------------
#define RCH 4

__global__ __launch_bounds__(256) void fused_tail5(const _Float16* __restrict__ h2t,
                                                   const _Float16* __restrict__ wpack,
                                                   const float* __restrict__ a1b,
                                                   const float* __restrict__ a1bias,
                                                   const float* __restrict__ a2b,
                                                   const float* __restrict__ a2bias,
                                                   float* __restrict__ partials)
{
    __shared__ alignas(16) _Float16 stage[2][11264];  // 2 x 22KB
    __shared__ alignas(16) _Float16 act[4][2048];     // per-wave, 2 tiles (16KB)

    const int tid = threadIdx.x;
    const int l = tid & 63, w = tid >> 6;
    const int c = l & 15, q = l >> 4;
    const int row0  = blockIdx.x * 128;
    const int rbase = blockIdx.y * RCH;
    const float b1s = a1bias[0], b2s = a2bias[0];

    const unsigned trl   = l * 8;
    const unsigned abase = lds_off(&act[w][0]);

    float b1v[RCH][4], b2v[RCH][4];
#pragma unroll
    for (int rl = 0; rl < RCH; ++rl)
#pragma unroll
        for (int nt = 0; nt < 4; ++nt) {
            b1v[rl][nt] = a1b[(rbase + rl) * 64 + nt * 16 + c] + b1s;
            b2v[rl][nt] = a2b[(rbase + rl) * 64 + nt * 16 + c] + b2s;
        }

    auto STAGE = [&](int rl, int b) {
        const int r = rbase + rl;
        const _Float16* hsrc = h2t + ((size_t)r * 256 + blockIdx.x * 8) * 256;
        const _Float16* wsrc = wpack + (size_t)r * 9216;
#pragma unroll
        for (int i = 0; i < 6; ++i) {
            const int ch = i * 4 + w;
            if (ch < 22) {
                const _Float16* src = (ch < 4) ? (hsrc + ch * 512) : (wsrc + (ch - 4) * 512);
                __builtin_amdgcn_global_load_lds(
                    (const __attribute__((address_space(1))) void*)(src + l * 8),
                    (__attribute__((address_space(3))) void*)&stage[b][ch * 512], 16, 0, 0);
            }
        }
    };

    STAGE(0, 0);
    __syncthreads();

    f32x4 accT[2][4] = {};
    int cur = 0;

#pragma unroll
    for (int rl = 0; rl < RCH; ++rl) {
        if (rl + 1 < RCH) STAGE(rl + 1, cur ^ 1);

        const _Float16* sp = &stage[cur][0];
        const unsigned sbytes = lds_off(sp);

        // ---- phase A: a[j] = leaky(h_tile[j] @ W1r + bias)
        h4_t ha0 = tr16(sbytes + (unsigned)(w) * 512 + trl);
        h4_t ha1 = tr16(sbytes + (unsigned)(w + 4) * 512 + trl);
        lgkm0();
        f32x4 pa[2][4];
#pragma unroll
        for (int nt = 0; nt < 4; ++nt) {
            h4_t bf = *reinterpret_cast<const h4_t*>(&sp[2048 + nt * 256 + l * 4]);
            pa[0][nt] = __builtin_amdgcn_mfma_f32_16x16x16f16(ha0, bf, (f32x4){0.f,0.f,0.f,0.f}, 0, 0, 0);
            pa[1][nt] = __builtin_amdgcn_mfma_f32_16x16x16f16(ha1, bf, (f32x4){0.f,0.f,0.f,0.f}, 0, 0, 0);
        }
#pragma unroll
        for (int j = 0; j < 2; ++j)
#pragma unroll
            for (int nt = 0; nt < 4; ++nt) {
                h4_t pk;
#pragma unroll
                for (int rg = 0; rg < 4; ++rg) {
                    float v = pa[j][nt][rg] + b1v[rl][nt];
                    pk[rg] = (_Float16)fmaxf(v, NEG_SLOPE * v);
                }
                const int kk = nt * 16 + c;
                const int hh = (kk >> 2) & 1;
                const int kp = (kk & 3) | ((kk >> 3) << 2);
                *reinterpret_cast<h4_t*>(&act[w][j * 1024 + hh * 512 + kp * 16 + q * 4]) = pk;
            }
        lgkm0();

        // ---- phase B: a2[j] = leaky(a[j] @ W2r + bias)
        h8_t afB[2][2];
#pragma unroll
        for (int j = 0; j < 2; ++j)
#pragma unroll
            for (int kt = 0; kt < 2; ++kt) {
                h4_t lo = tr16(abase + (unsigned)(j * 2048 + kt * 512) + trl);
                h4_t hi = tr16(abase + (unsigned)(j * 2048 + 1024 + kt * 512) + trl);
                afB[j][kt] = __builtin_shufflevector(lo, hi, 0, 1, 2, 3, 4, 5, 6, 7);
            }
        lgkm0();
        f32x4 pb[2][4] = {};
#pragma unroll
        for (int kt = 0; kt < 2; ++kt)
#pragma unroll
            for (int nt = 0; nt < 4; ++nt) {
                h8_t bf = *reinterpret_cast<const h8_t*>(&sp[3072 + kt * 2048 + nt * 512 + l * 8]);
                pb[0][nt] = __builtin_amdgcn_mfma_f32_16x16x32_f16(afB[0][kt], bf, pb[0][nt], 0, 0, 0);
                pb[1][nt] = __builtin_amdgcn_mfma_f32_16x16x32_f16(afB[1][kt], bf, pb[1][nt], 0, 0, 0);
            }
#pragma unroll
        for (int j = 0; j < 2; ++j)
#pragma unroll
            for (int nt = 0; nt < 4; ++nt) {
                h4_t pk;
#pragma unroll
                for (int rg = 0; rg < 4; ++rg) {
                    float v = pb[j][nt][rg] + b2v[rl][nt];
                    pk[rg] = (_Float16)fmaxf(v, NEG_SLOPE * v);
                }
                const int kk = nt * 16 + c;
                const int hh = (kk >> 2) & 1;
                const int kp = (kk & 3) | ((kk >> 3) << 2);
                *reinterpret_cast<h4_t*>(&act[w][j * 1024 + hh * 512 + kp * 16 + q * 4]) = pk;
            }
        lgkm0();

        // ---- phase C: t2[j] += a2[j] @ WpR
        h8_t afC[2][2];
#pragma unroll
        for (int j = 0; j < 2; ++j)
#pragma unroll
            for (int kt = 0; kt < 2; ++kt) {
                h4_t lo = tr16(abase + (unsigned)(j * 2048 + kt * 512) + trl);
                h4_t hi = tr16(abase + (unsigned)(j * 2048 + 1024 + kt * 512) + trl);
                afC[j][kt] = __builtin_shufflevector(lo, hi, 0, 1, 2, 3, 4, 5, 6, 7);
            }
        lgkm0();
#pragma unroll
        for (int kt = 0; kt < 2; ++kt)
#pragma unroll
            for (int nt = 0; nt < 4; ++nt) {
                h8_t bf = *reinterpret_cast<const h8_t*>(&sp[7168 + kt * 2048 + nt * 512 + l * 8]);
                accT[0][nt] = __builtin_amdgcn_mfma_f32_16x16x32_f16(afC[0][kt], bf, accT[0][nt], 0, 0, 0);
                accT[1][nt] = __builtin_amdgcn_mfma_f32_16x16x32_f16(afC[1][kt], bf, accT[1][nt], 0, 0, 0);
            }

        __syncthreads();
        cur ^= 1;
    }

#pragma unroll
    for (int j = 0; j < 2; ++j)
#pragma unroll
        for (int nt = 0; nt < 4; ++nt)
#pragma unroll
            for (int rg = 0; rg < 4; ++rg)
                partials[((size_t)blockIdx.y * 4096 + row0 + (w + 4 * j) * 16 + q * 4 + rg) * 64
                         + nt * 16 + c] = accT[j][nt][rg];
}

// ---------------------------------------------------------------------------
// K5: reduce 16 partials + bp2, dot with Wl, add bl -> out[4096]  (R11)
// ---------------------------------------------------------------------------
__global__ __launch_bounds__(256) void reduce_out(const float* __restrict__ partials,
                                                  const float* __restrict__ bp2,
                                                  const float* __restrict__ Wl,
                                                  const float* __restrict__ bl,
                                                  float* __restrict__ out)
{
    const int tid = threadIdx.x;
    const int row = blockIdx.x * 4 + (tid >> 6);
    const int col = tid & 63;
    float s = bp2[col];
#pragma unroll
    for (int c = 0; c < 16; ++c)
        s += partials[(size_t)c * 262144 + (size_t)row * 64 + col];
    s *= Wl[col];
    s += __shfl_xor(s, 1);
    s += __shfl_xor(s, 2);
    s += __shfl_xor(s, 4);
    s += __shfl_xor(s, 8);
    s += __shfl_xor(s, 16);
    s += __shfl_xor(s, 32);
    if (col == 0) out[row] = s + bl[0];
}

// ---------------------------------------------------------------------------
extern "C" void kernel_launch(void* const* d_in, const int* in_sizes, int n_in,
                              void* d_out, int out_size, void* d_ws, size_t ws_size,
                              hipStream_t stream)
{
    const float* x      = (const float*)d_in[0];
    const float* Wpca   = (const float*)d_in[1];
    const float* bpca   = (const float*)d_in[2];
    const float* W1     = (const float*)d_in[3];
    const float* b1     = (const float*)d_in[4];
    const float* W2     = (const float*)d_in[5];
    const float* b2     = (const float*)d_in[6];
    const float* a1W    = (const float*)d_in[7];
    const float* a1b    = (const float*)d_in[8];
    const float* a1bias = (const float*)d_in[9];
    const float* a2W    = (const float*)d_in[10];
    const float* a2b    = (const float*)d_in[11];
    const float* a2bias = (const float*)d_in[12];
    const float* Wp2    = (const float*)d_in[13];
    const float* bp2    = (const float*)d_in[14];
    const float* Wl     = (const float*)d_in[15];
    const float* bl     = (const float*)d_in[16];
    float* out = (float*)d_out;

    // workspace layout (bytes) — verified non-overlapping:
    //   h1h [1M,9M)  h2t [9M,17M)  W2T [17M,19M)  wpack [19M,20.13M)
    //   W1T [21M,21.13M)  partials [22M,38.8M)  tpart aliases h2t (dead then)
    char* wsb = (char*)d_ws;
    _Float16* h1h      = (_Float16*)(wsb + (1ull  << 20));
    _Float16* h2t      = (_Float16*)(wsb + (9ull  << 20));
    _Float16* W2T      = (_Float16*)(wsb + (17ull << 20));
    _Float16* wpack    = (_Float16*)(wsb + (19ull << 20));
    _Float16* W1T      = (_Float16*)(wsb + (21ull << 20));
    float*    partials = (float*)   (wsb + (22ull << 20));
    float*    tpart    = (float*)   (wsb + (9ull  << 20));

    // K0: prep (W2T+W1T+wpack) || split-K t-partials, one launch
    prep_and_splitk<<<dim3(4416), 256, 0, stream>>>(W2, W1, a1W, a2W, Wp2, x, Wpca,
                                                    W2T, W1T, wpack, tpart);
    // K2': h1 = leaky((sum tpart + bpca) @ W1 + b1), combine fused into staging
    gemm_k64_mfma_fused<<<dim3(8, 32), 256, 0, stream>>>(tpart, bpca, W1T, b1, h1h);
    // K3: h2 (packed) = leaky(h1 @ W2 + b2) via MFMA
    gemm_mfma_f16_v2<<<dim3(8, 64), 256, 0, stream>>>(h1h, W2T, b2, h2t);
    // K4: fused additive chain -> partials
    fused_tail5<<<dim3(32, 16), 256, 0, stream>>>(h2t, wpack, a1b, a1bias,
                                                  a2b, a2bias, partials);
    // K5: reduce partials + PCA2 bias + last layer
    reduce_out<<<dim3(1024), 256, 0, stream>>>(partials, bp2, Wl, bl, out);
}

// Round 14
// 67.137 us; speedup vs baseline: 1.0857x; 1.0857x over previous
//
#include <hip/hip_runtime.h>

#define NEG_SLOPE 0.1f

__device__ __forceinline__ float leaky(float v) { return v > 0.0f ? v : NEG_SLOPE * v; }

typedef _Float16 h4_t __attribute__((ext_vector_type(4)));
typedef _Float16 h8_t __attribute__((ext_vector_type(8)));
typedef float f32x4 __attribute__((ext_vector_type(4)));

__device__ __forceinline__ unsigned lds_off(const void* p) {
    return (unsigned)(unsigned long long)p;
}

__device__ __forceinline__ void lgkm0() {
    asm volatile("s_waitcnt lgkmcnt(0)" ::: "memory");
    __builtin_amdgcn_sched_barrier(0);        // rule #18
}

__device__ __forceinline__ h4_t tr16(unsigned addr) {
    h4_t d;
    asm volatile("ds_read_b64_tr_b16 %0, %1" : "=v"(d) : "v"(addr) : "memory");
    return d;
}

// ---------------------------------------------------------------------------
// K0: merged PREP (W2T + W1T + wpack, K=32 B-frag pack) || split-K GEMM.
// blocks [0,1024): W2T; [1024,1088): W1T; [1088,3392): pack;
// blocks [3392,4416): splitk for t-partials. (R13 kernel, kept — bisect.)
// ---------------------------------------------------------------------------
__global__ __launch_bounds__(256) void prep_and_splitk(const float* __restrict__ W2,
                                                       const float* __restrict__ W1,
                                                       const float* __restrict__ a1W,
                                                       const float* __restrict__ a2W,
                                                       const float* __restrict__ Wp2,
                                                       const float* __restrict__ x,
                                                       const float* __restrict__ Wpca,
                                                       _Float16* __restrict__ W2T,
                                                       _Float16* __restrict__ W1T,
                                                       _Float16* __restrict__ wpack,
                                                       float* __restrict__ P)
{
    __shared__ float tile[32][33];
    __shared__ alignas(16) float As[32][33];
    __shared__ alignas(16) float Bs[32][64];
    const int b   = blockIdx.x;
    const int tid = threadIdx.x;

    if (b < 1024) {                         // W2T[n][k] = fp16 W2[k][n]
        const int n0 = (b & 31) * 32, k0 = (b >> 5) * 32;
        const int r = tid >> 3, c4 = (tid & 7) * 4;
        float4 v = *reinterpret_cast<const float4*>(&W2[(size_t)(k0 + r) * 1024 + n0 + c4]);
        tile[r][c4 + 0] = v.x; tile[r][c4 + 1] = v.y;
        tile[r][c4 + 2] = v.z; tile[r][c4 + 3] = v.w;
        __syncthreads();
        h4_t o;
        o[0] = (_Float16)tile[c4 + 0][r]; o[1] = (_Float16)tile[c4 + 1][r];
        o[2] = (_Float16)tile[c4 + 2][r]; o[3] = (_Float16)tile[c4 + 3][r];
        *reinterpret_cast<h4_t*>(&W2T[(size_t)(n0 + r) * 1024 + k0 + c4]) = o;
    } else if (b < 1088) {                  // W1T[n][k] = fp16 W1[k][n]  (k<64)
        const int b2 = b - 1024;
        const int n0 = (b2 & 31) * 32, k0 = (b2 >> 5) * 32;
        const int r = tid >> 3, c4 = (tid & 7) * 4;
        float4 v = *reinterpret_cast<const float4*>(&W1[(size_t)(k0 + r) * 1024 + n0 + c4]);
        tile[r][c4 + 0] = v.x; tile[r][c4 + 1] = v.y;
        tile[r][c4 + 2] = v.z; tile[r][c4 + 3] = v.w;
        __syncthreads();
        h4_t o;
        o[0] = (_Float16)tile[c4 + 0][r]; o[1] = (_Float16)tile[c4 + 1][r];
        o[2] = (_Float16)tile[c4 + 2][r]; o[3] = (_Float16)tile[c4 + 3][r];
        *reinterpret_cast<h4_t*>(&W1T[(size_t)(n0 + r) * 64 + k0 + c4]) = o;
    } else if (b < 3392) {                  // pack tail weights (K=32 B-frag)
        const int idx = (b - 1088) * 256 + tid;   // < 589824
        if (idx < 589824) {
            const int r = idx / 9216, qq = idx % 9216;
            float v;
            if (qq < 1024) {
                int nt = qq >> 8, rem = qq & 255, l = rem >> 2, j = rem & 3;
                int n = nt * 16 + (l & 15), k = (l >> 4) * 4 + j;
                v = a1W[(size_t)r * 1024 + k * 64 + n];
            } else if (qq < 5120) {
                int p = qq - 1024, kt = p >> 11, u = p & 2047, nt = u >> 9, s = u & 511,
                    l = s >> 3, j = s & 7;
                int n = nt * 16 + (l & 15), k = kt * 32 + (l >> 4) * 8 + j;
                v = a2W[(size_t)r * 4096 + k * 64 + n];
            } else {
                int p = qq - 5120, kt = p >> 11, u = p & 2047, nt = u >> 9, s = u & 511,
                    l = s >> 3, j = s & 7;
                int n = nt * 16 + (l & 15), k = kt * 32 + (l >> 4) * 8 + j;
                v = Wp2[((size_t)r * 64 + k) * 64 + n];
            }
            wpack[idx] = (_Float16)v;
        }
    } else {                                // split-K: t partials [8][4096][64]
        const int b2    = b - 3392;
        const int row0  = (b2 & 127) * 32;
        const int kbase = (b2 >> 7) * 128;
        const int r0    = (tid >> 4) * 2;
        const int c0    = (tid & 15) * 4;
        const int am    = tid >> 3;
        const int ak    = (tid & 7) * 4;
        float acc[2][4] = {};

#pragma unroll
        for (int kc = 0; kc < 128; kc += 32) {
            const int k0 = kbase + kc;
            float4 va = *reinterpret_cast<const float4*>(&x[(size_t)(row0 + am) * 1024 + k0 + ak]);
            As[ak + 0][am] = va.x; As[ak + 1][am] = va.y;
            As[ak + 2][am] = va.z; As[ak + 3][am] = va.w;
#pragma unroll
            for (int p = 0; p < 2; ++p) {
                int idx = tid + p * 256;
                int kk  = idx >> 4;
                int nq  = (idx & 15) * 4;
                *reinterpret_cast<float4*>(&Bs[kk][nq]) =
                    *reinterpret_cast<const float4*>(&Wpca[(size_t)(k0 + kk) * 64 + nq]);
            }
            __syncthreads();
#pragma unroll
            for (int k = 0; k < 32; ++k) {
                float a0 = As[k][r0], a1 = As[k][r0 + 1];
                float4 bv = *reinterpret_cast<const float4*>(&Bs[k][c0]);
                acc[0][0] = fmaf(a0, bv.x, acc[0][0]); acc[0][1] = fmaf(a0, bv.y, acc[0][1]);
                acc[0][2] = fmaf(a0, bv.z, acc[0][2]); acc[0][3] = fmaf(a0, bv.w, acc[0][3]);
                acc[1][0] = fmaf(a1, bv.x, acc[1][0]); acc[1][1] = fmaf(a1, bv.y, acc[1][1]);
                acc[1][2] = fmaf(a1, bv.z, acc[1][2]); acc[1][3] = fmaf(a1, bv.w, acc[1][3]);
            }
            __syncthreads();
        }
#pragma unroll
        for (int i = 0; i < 2; ++i) {
            float4 o; o.x = acc[i][0]; o.y = acc[i][1]; o.z = acc[i][2]; o.w = acc[i][3];
            *reinterpret_cast<float4*>(
                &P[((size_t)(b2 >> 7) * 4096 + row0 + r0 + i) * 64 + c0]) = o;
        }
    }
}

// K1b: t16 = fp16(sum_c P[c] + bias)   (restored R11 — K2 fusion reverted)
__global__ __launch_bounds__(256) void combine_t16(const float* __restrict__ P,
                                                   const float* __restrict__ bias,
                                                   _Float16* __restrict__ t16)
{
    const int idx = blockIdx.x * 256 + threadIdx.x;
    float s = bias[idx & 63];
#pragma unroll
    for (int c = 0; c < 8; ++c)
        s += P[(size_t)c * 262144 + idx];
    t16[idx] = (_Float16)s;
}

// ---------------------------------------------------------------------------
// K2: h1[4096][1024] = leaky(t16 @ W1 + b1) via fp16 MFMA (K=64). (R11)
// ---------------------------------------------------------------------------
__global__ __launch_bounds__(256) void gemm_k64_mfma(const _Float16* __restrict__ A,
                                                     const _Float16* __restrict__ BT,
                                                     const float* __restrict__ bias,
                                                     _Float16* __restrict__ C)
{
    __shared__ alignas(16) _Float16 As[128 * 64];
    __shared__ alignas(16) _Float16 Bs[128 * 64];
    const int tid = threadIdx.x;
    const int l   = tid & 63;
    const int w   = tid >> 6;
    const int wm  = w >> 1;
    const int wn  = w & 1;
    const int bm0 = blockIdx.y * 128;
    const int bn0 = blockIdx.x * 128;
    const int fr  = l & 15;
    const int fg  = l >> 4;
    const int srow  = l >> 3;
    const int sslot = l & 7;

#pragma unroll
    for (int i = 0; i < 4; ++i) {
        const int r0   = w * 32 + i * 8;
        const int rowA = r0 + srow;
        const int slot = sslot ^ (rowA & 7);
        __builtin_amdgcn_global_load_lds(
            (const __attribute__((address_space(1))) void*)&A[(size_t)(bm0 + rowA) * 64 + slot * 8],
            (__attribute__((address_space(3))) void*)&As[r0 * 64], 16, 0, 0);
        __builtin_amdgcn_global_load_lds(
            (const __attribute__((address_space(1))) void*)&BT[(size_t)(bn0 + rowA) * 64 + slot * 8],
            (__attribute__((address_space(3))) void*)&Bs[r0 * 64], 16, 0, 0);
    }
    __syncthreads();

    f32x4 acc[4][4] = {};
#pragma unroll
    for (int ks = 0; ks < 2; ++ks) {
        h8_t af[4], bf[4];
#pragma unroll
        for (int mt = 0; mt < 4; ++mt) {
            int row = wm * 64 + mt * 16 + fr;
            int sg  = ks * 4 + fg;
            af[mt] = *reinterpret_cast<const h8_t*>(&As[row * 64 + ((sg ^ (row & 7)) << 3)]);
        }
#pragma unroll
        for (int nt = 0; nt < 4; ++nt) {
            int row = wn * 64 + nt * 16 + fr;
            int sg  = ks * 4 + fg;
            bf[nt] = *reinterpret_cast<const h8_t*>(&Bs[row * 64 + ((sg ^ (row & 7)) << 3)]);
        }
#pragma unroll
        for (int mt = 0; mt < 4; ++mt)
#pragma unroll
            for (int nt = 0; nt < 4; ++nt)
                acc[mt][nt] = __builtin_amdgcn_mfma_f32_16x16x32_f16(af[mt], bf[nt],
                                                                     acc[mt][nt], 0, 0, 0);
    }

#pragma unroll
    for (int nt = 0; nt < 4; ++nt) {
        const int col = bn0 + wn * 64 + nt * 16 + fr;
        const float bv = bias[col];
#pragma unroll
        for (int mt = 0; mt < 4; ++mt)
#pragma unroll
            for (int rg = 0; rg < 4; ++rg) {
                const int row = bm0 + wm * 64 + mt * 16 + fg * 4 + rg;
                float v = acc[mt][nt][rg] + bv;
                C[(size_t)row * 1024 + col] = (_Float16)fmaxf(v, NEG_SLOPE * v);
            }
    }
}

// ---------------------------------------------------------------------------
// K3 v2: h2t = pack(leaky(h1 @ W2 + b2)). (R11)
// ---------------------------------------------------------------------------
__global__ __launch_bounds__(256) void gemm_mfma_f16_v2(const _Float16* __restrict__ A,
                                                        const _Float16* __restrict__ BT,
                                                        const float* __restrict__ bias,
                                                        _Float16* __restrict__ h2t)
{
    __shared__ alignas(16) _Float16 As[64 * 64];
    __shared__ alignas(16) _Float16 Bs[128 * 64];
    const int tid = threadIdx.x;
    const int l   = tid & 63;
    const int w   = tid >> 6;
    const int wm  = w >> 1;
    const int wn  = w & 1;
    const int bm0 = blockIdx.y * 64;
    const int bn0 = blockIdx.x * 128;
    const int fr  = l & 15;
    const int fg  = l >> 4;
    const int srow  = l >> 3;
    const int sslot = l & 7;

    f32x4 acc[2][4] = {};

    for (int k0 = 0; k0 < 1024; k0 += 64) {
#pragma unroll
        for (int i = 0; i < 2; ++i) {
            const int r0   = w * 16 + i * 8;
            const int rowA = r0 + srow;
            const int slot = sslot ^ (rowA & 7);
            __builtin_amdgcn_global_load_lds(
                (const __attribute__((address_space(1))) void*)&A[(size_t)(bm0 + rowA) * 1024 + k0 + slot * 8],
                (__attribute__((address_space(3))) void*)&As[r0 * 64], 16, 0, 0);
        }
#pragma unroll
        for (int i = 0; i < 4; ++i) {
            const int r0   = w * 32 + i * 8;
            const int rowB = r0 + srow;
            const int slot = sslot ^ (rowB & 7);
            __builtin_amdgcn_global_load_lds(
                (const __attribute__((address_space(1))) void*)&BT[(size_t)(bn0 + rowB) * 1024 + k0 + slot * 8],
                (__attribute__((address_space(3))) void*)&Bs[r0 * 64], 16, 0, 0);
        }
        __syncthreads();

#pragma unroll
        for (int ks = 0; ks < 2; ++ks) {
            h8_t af[2], bf[4];
#pragma unroll
            for (int mt = 0; mt < 2; ++mt) {
                int row = wm * 32 + mt * 16 + fr;
                int sg  = ks * 4 + fg;
                af[mt] = *reinterpret_cast<const h8_t*>(&As[row * 64 + ((sg ^ (row & 7)) << 3)]);
            }
#pragma unroll
            for (int nt = 0; nt < 4; ++nt) {
                int row = wn * 64 + nt * 16 + fr;
                int sg  = ks * 4 + fg;
                bf[nt] = *reinterpret_cast<const h8_t*>(&Bs[row * 64 + ((sg ^ (row & 7)) << 3)]);
            }
#pragma unroll
            for (int mt = 0; mt < 2; ++mt)
#pragma unroll
                for (int nt = 0; nt < 4; ++nt)
                    acc[mt][nt] = __builtin_amdgcn_mfma_f32_16x16x32_f16(af[mt], bf[nt],
                                                                         acc[mt][nt], 0, 0, 0);
        }
        __syncthreads();
    }

    const int rblk0 = (bm0 >> 4) + wm * 2;
    const int cblk0 = (bn0 >> 4) + wn * 4;
#pragma unroll
    for (int nt = 0; nt < 4; ++nt) {
        const int col = bn0 + wn * 64 + nt * 16 + fr;
        const float bv = bias[col];
#pragma unroll
        for (int mt = 0; mt < 2; ++mt) {
            h4_t pk;
#pragma unroll
            for (int r = 0; r < 4; ++r) {
                float v = acc[mt][nt][r] + bv;
                pk[r] = (_Float16)fmaxf(v, NEG_SLOPE * v);
            }
            *reinterpret_cast<h4_t*>(
                &h2t[(((size_t)(cblk0 + nt) * 256 + rblk0 + mt) * 16 + fr) * 16 + fg * 4]) = pk;
        }
    }
}

// ---------------------------------------------------------------------------
// K4: fused additive chain v5 (byte-identical to passing round 11).
// ---------------------------------------------------------------------------
#define RCH 4

__global__ __launch_bounds__(256) void fused_tail5(const _Float16* __restrict__ h2t,
                                                   const _Float16* __restrict__ wpack,
                                                   const float* __restrict__ a1b,
                                                   const float* __restrict__ a1bias,
                                                   const float* __restrict__ a2b,
                                                   const float* __restrict__ a2bias,
                                                   float* __restrict__ partials)
{
    __shared__ alignas(16) _Float16 stage[2][11264];  // 2 x 22KB
    __shared__ alignas(16) _Float16 act[4][2048];     // per-wave, 2 tiles (16KB)

    const int tid = threadIdx.x;
    const int l = tid & 63, w = tid >> 6;
    const int c = l & 15, q = l >> 4;
    const int row0  = blockIdx.x * 128;
    const int rbase = blockIdx.y * RCH;
    const float b1s = a1bias[0], b2s = a2bias[0];

    const unsigned trl   = l * 8;
    const unsigned abase = lds_off(&act[w][0]);

    float b1v[RCH][4], b2v[RCH][4];
#pragma unroll
    for (int rl = 0; rl < RCH; ++rl)
#pragma unroll
        for (int nt = 0; nt < 4; ++nt) {
            b1v[rl][nt] = a1b[(rbase + rl) * 64 + nt * 16 + c] + b1s;
            b2v[rl][nt] = a2b[(rbase + rl) * 64 + nt * 16 + c] + b2s;
        }

    auto STAGE = [&](int rl, int b) {
        const int r = rbase + rl;
        const _Float16* hsrc = h2t + ((size_t)r * 256 + blockIdx.x * 8) * 256;
        const _Float16* wsrc = wpack + (size_t)r * 9216;
#pragma unroll
        for (int i = 0; i < 6; ++i) {
            const int ch = i * 4 + w;
            if (ch < 22) {
                const _Float16* src = (ch < 4) ? (hsrc + ch * 512) : (wsrc + (ch - 4) * 512);
                __builtin_amdgcn_global_load_lds(
                    (const __attribute__((address_space(1))) void*)(src + l * 8),
                    (__attribute__((address_space(3))) void*)&stage[b][ch * 512], 16, 0, 0);
            }
        }
    };

    STAGE(0, 0);
    __syncthreads();

    f32x4 accT[2][4] = {};
    int cur = 0;

#pragma unroll
    for (int rl = 0; rl < RCH; ++rl) {
        if (rl + 1 < RCH) STAGE(rl + 1, cur ^ 1);

        const _Float16* sp = &stage[cur][0];
        const unsigned sbytes = lds_off(sp);

        // ---- phase A: a[j] = leaky(h_tile[j] @ W1r + bias)
        h4_t ha0 = tr16(sbytes + (unsigned)(w) * 512 + trl);
        h4_t ha1 = tr16(sbytes + (unsigned)(w + 4) * 512 + trl);
        lgkm0();
        f32x4 pa[2][4];
#pragma unroll
        for (int nt = 0; nt < 4; ++nt) {
            h4_t bf = *reinterpret_cast<const h4_t*>(&sp[2048 + nt * 256 + l * 4]);
            pa[0][nt] = __builtin_amdgcn_mfma_f32_16x16x16f16(ha0, bf, (f32x4){0.f,0.f,0.f,0.f}, 0, 0, 0);
            pa[1][nt] = __builtin_amdgcn_mfma_f32_16x16x16f16(ha1, bf, (f32x4){0.f,0.f,0.f,0.f}, 0, 0, 0);
        }
#pragma unroll
        for (int j = 0; j < 2; ++j)
#pragma unroll
            for (int nt = 0; nt < 4; ++nt) {
                h4_t pk;
#pragma unroll
                for (int rg = 0; rg < 4; ++rg) {
                    float v = pa[j][nt][rg] + b1v[rl][nt];
                    pk[rg] = (_Float16)fmaxf(v, NEG_SLOPE * v);
                }
                const int kk = nt * 16 + c;
                const int hh = (kk >> 2) & 1;
                const int kp = (kk & 3) | ((kk >> 3) << 2);
                *reinterpret_cast<h4_t*>(&act[w][j * 1024 + hh * 512 + kp * 16 + q * 4]) = pk;
            }
        lgkm0();

        // ---- phase B: a2[j] = leaky(a[j] @ W2r + bias)
        h8_t afB[2][2];
#pragma unroll
        for (int j = 0; j < 2; ++j)
#pragma unroll
            for (int kt = 0; kt < 2; ++kt) {
                h4_t lo = tr16(abase + (unsigned)(j * 2048 + kt * 512) + trl);
                h4_t hi = tr16(abase + (unsigned)(j * 2048 + 1024 + kt * 512) + trl);
                afB[j][kt] = __builtin_shufflevector(lo, hi, 0, 1, 2, 3, 4, 5, 6, 7);
            }
        lgkm0();
        f32x4 pb[2][4] = {};
#pragma unroll
        for (int kt = 0; kt < 2; ++kt)
#pragma unroll
            for (int nt = 0; nt < 4; ++nt) {
                h8_t bf = *reinterpret_cast<const h8_t*>(&sp[3072 + kt * 2048 + nt * 512 + l * 8]);
                pb[0][nt] = __builtin_amdgcn_mfma_f32_16x16x32_f16(afB[0][kt], bf, pb[0][nt], 0, 0, 0);
                pb[1][nt] = __builtin_amdgcn_mfma_f32_16x16x32_f16(afB[1][kt], bf, pb[1][nt], 0, 0, 0);
            }
#pragma unroll
        for (int j = 0; j < 2; ++j)
#pragma unroll
            for (int nt = 0; nt < 4; ++nt) {
                h4_t pk;
#pragma unroll
                for (int rg = 0; rg < 4; ++rg) {
                    float v = pb[j][nt][rg] + b2v[rl][nt];
                    pk[rg] = (_Float16)fmaxf(v, NEG_SLOPE * v);
                }
                const int kk = nt * 16 + c;
                const int hh = (kk >> 2) & 1;
                const int kp = (kk & 3) | ((kk >> 3) << 2);
                *reinterpret_cast<h4_t*>(&act[w][j * 1024 + hh * 512 + kp * 16 + q * 4]) = pk;
            }
        lgkm0();

        // ---- phase C: t2[j] += a2[j] @ WpR
        h8_t afC[2][2];
#pragma unroll
        for (int j = 0; j < 2; ++j)
#pragma unroll
            for (int kt = 0; kt < 2; ++kt) {
                h4_t lo = tr16(abase + (unsigned)(j * 2048 + kt * 512) + trl);
                h4_t hi = tr16(abase + (unsigned)(j * 2048 + 1024 + kt * 512) + trl);
                afC[j][kt] = __builtin_shufflevector(lo, hi, 0, 1, 2, 3, 4, 5, 6, 7);
            }
        lgkm0();
#pragma unroll
        for (int kt = 0; kt < 2; ++kt)
#pragma unroll
            for (int nt = 0; nt < 4; ++nt) {
                h8_t bf = *reinterpret_cast<const h8_t*>(&sp[7168 + kt * 2048 + nt * 512 + l * 8]);
                accT[0][nt] = __builtin_amdgcn_mfma_f32_16x16x32_f16(afC[0][kt], bf, accT[0][nt], 0, 0, 0);
                accT[1][nt] = __builtin_amdgcn_mfma_f32_16x16x32_f16(afC[1][kt], bf, accT[1][nt], 0, 0, 0);
            }

        __syncthreads();
        cur ^= 1;
    }

#pragma unroll
    for (int j = 0; j < 2; ++j)
#pragma unroll
        for (int nt = 0; nt < 4; ++nt)
#pragma unroll
            for (int rg = 0; rg < 4; ++rg)
                partials[((size_t)blockIdx.y * 4096 + row0 + (w + 4 * j) * 16 + q * 4 + rg) * 64
                         + nt * 16 + c] = accT[j][nt][rg];
}

// ---------------------------------------------------------------------------
// K5: reduce 16 partials + bp2, dot with Wl, add bl -> out[4096]  (R11)
// ---------------------------------------------------------------------------
__global__ __launch_bounds__(256) void reduce_out(const float* __restrict__ partials,
                                                  const float* __restrict__ bp2,
                                                  const float* __restrict__ Wl,
                                                  const float* __restrict__ bl,
                                                  float* __restrict__ out)
{
    const int tid = threadIdx.x;
    const int row = blockIdx.x * 4 + (tid >> 6);
    const int col = tid & 63;
    float s = bp2[col];
#pragma unroll
    for (int c = 0; c < 16; ++c)
        s += partials[(size_t)c * 262144 + (size_t)row * 64 + col];
    s *= Wl[col];
    s += __shfl_xor(s, 1);
    s += __shfl_xor(s, 2);
    s += __shfl_xor(s, 4);
    s += __shfl_xor(s, 8);
    s += __shfl_xor(s, 16);
    s += __shfl_xor(s, 32);
    if (col == 0) out[row] = s + bl[0];
}

// ---------------------------------------------------------------------------
extern "C" void kernel_launch(void* const* d_in, const int* in_sizes, int n_in,
                              void* d_out, int out_size, void* d_ws, size_t ws_size,
                              hipStream_t stream)
{
    const float* x      = (const float*)d_in[0];
    const float* Wpca   = (const float*)d_in[1];
    const float* bpca   = (const float*)d_in[2];
    const float* W1     = (const float*)d_in[3];
    const float* b1     = (const float*)d_in[4];
    const float* W2     = (const float*)d_in[5];
    const float* b2     = (const float*)d_in[6];
    const float* a1W    = (const float*)d_in[7];
    const float* a1b    = (const float*)d_in[8];
    const float* a1bias = (const float*)d_in[9];
    const float* a2W    = (const float*)d_in[10];
    const float* a2b    = (const float*)d_in[11];
    const float* a2bias = (const float*)d_in[12];
    const float* Wp2    = (const float*)d_in[13];
    const float* bp2    = (const float*)d_in[14];
    const float* Wl     = (const float*)d_in[15];
    const float* bl     = (const float*)d_in[16];
    float* out = (float*)d_out;

    // workspace layout (bytes) — verified non-overlapping:
    //   t16 [0,0.5M)  h1h [1M,9M)  h2t [9M,17M)  W2T [17M,19M)
    //   wpack [19M,20.13M)  W1T [21M,21.13M)  partials [22M,38.8M)
    char* wsb = (char*)d_ws;
    _Float16* t16      = (_Float16*)(wsb);
    _Float16* h1h      = (_Float16*)(wsb + (1ull  << 20));
    _Float16* h2t      = (_Float16*)(wsb + (9ull  << 20));
    _Float16* W2T      = (_Float16*)(wsb + (17ull << 20));
    _Float16* wpack    = (_Float16*)(wsb + (19ull << 20));
    _Float16* W1T      = (_Float16*)(wsb + (21ull << 20));
    float*    partials = (float*)   (wsb + (22ull << 20));
    float*    tpart    = (float*)   (wsb + (9ull  << 20));   // aliases h2t (dead then)

    // K0: prep (W2T+W1T+wpack) || split-K t-partials, one launch
    prep_and_splitk<<<dim3(4416), 256, 0, stream>>>(W2, W1, a1W, a2W, Wp2, x, Wpca,
                                                    W2T, W1T, wpack, tpart);
    // K1b: combine t partials -> fp16 (restored R11 standalone kernel)
    combine_t16<<<dim3(1024), 256, 0, stream>>>(tpart, bpca, t16);
    // K2: h1 = leaky(t @ W1 + b1) via MFMA (K=64)
    gemm_k64_mfma<<<dim3(8, 32), 256, 0, stream>>>(t16, W1T, b1, h1h);
    // K3: h2 (packed) = leaky(h1 @ W2 + b2) via MFMA
    gemm_mfma_f16_v2<<<dim3(8, 64), 256, 0, stream>>>(h1h, W2T, b2, h2t);
    // K4: fused additive chain -> partials
    fused_tail5<<<dim3(32, 16), 256, 0, stream>>>(h2t, wpack, a1b, a1bias,
                                                  a2b, a2bias, partials);
    // K5: reduce partials + PCA2 bias + last layer
    reduce_out<<<dim3(1024), 256, 0, stream>>>(partials, bp2, Wl, bl, out);
}

// Round 15
// 63.947 us; speedup vs baseline: 1.1399x; 1.0499x over previous
//
#include <hip/hip_runtime.h>

#define NEG_SLOPE 0.1f

__device__ __forceinline__ float leaky(float v) { return v > 0.0f ? v : NEG_SLOPE * v; }

typedef _Float16 h4_t __attribute__((ext_vector_type(4)));
typedef _Float16 h8_t __attribute__((ext_vector_type(8)));
typedef float f32x4 __attribute__((ext_vector_type(4)));

__device__ __forceinline__ unsigned lds_off(const void* p) {
    return (unsigned)(unsigned long long)p;
}

__device__ __forceinline__ void lgkm0() {
    asm volatile("s_waitcnt lgkmcnt(0)" ::: "memory");
    __builtin_amdgcn_sched_barrier(0);        // rule #18
}

__device__ __forceinline__ h4_t tr16(unsigned addr) {
    h4_t d;
    asm volatile("ds_read_b64_tr_b16 %0, %1" : "=v"(d) : "v"(addr) : "memory");
    return d;
}

// ---------------------------------------------------------------------------
// K0: merged PREP (W2T + W1T + wpack, K=32 B-frag pack) || split-K GEMM.
// blocks [0,1024): W2T; [1024,1088): W1T; [1088,3392): pack;
// blocks [3392,4416): splitk for t-partials.
// ---------------------------------------------------------------------------
__global__ __launch_bounds__(256) void prep_and_splitk(const float* __restrict__ W2,
                                                       const float* __restrict__ W1,
                                                       const float* __restrict__ a1W,
                                                       const float* __restrict__ a2W,
                                                       const float* __restrict__ Wp2,
                                                       const float* __restrict__ x,
                                                       const float* __restrict__ Wpca,
                                                       _Float16* __restrict__ W2T,
                                                       _Float16* __restrict__ W1T,
                                                       _Float16* __restrict__ wpack,
                                                       float* __restrict__ P)
{
    __shared__ float tile[32][33];
    __shared__ alignas(16) float As[32][33];
    __shared__ alignas(16) float Bs[32][64];
    const int b   = blockIdx.x;
    const int tid = threadIdx.x;

    if (b < 1024) {                         // W2T[n][k] = fp16 W2[k][n]
        const int n0 = (b & 31) * 32, k0 = (b >> 5) * 32;
        const int r = tid >> 3, c4 = (tid & 7) * 4;
        float4 v = *reinterpret_cast<const float4*>(&W2[(size_t)(k0 + r) * 1024 + n0 + c4]);
        tile[r][c4 + 0] = v.x; tile[r][c4 + 1] = v.y;
        tile[r][c4 + 2] = v.z; tile[r][c4 + 3] = v.w;
        __syncthreads();
        h4_t o;
        o[0] = (_Float16)tile[c4 + 0][r]; o[1] = (_Float16)tile[c4 + 1][r];
        o[2] = (_Float16)tile[c4 + 2][r]; o[3] = (_Float16)tile[c4 + 3][r];
        *reinterpret_cast<h4_t*>(&W2T[(size_t)(n0 + r) * 1024 + k0 + c4]) = o;
    } else if (b < 1088) {                  // W1T[n][k] = fp16 W1[k][n]  (k<64)
        const int b2 = b - 1024;
        const int n0 = (b2 & 31) * 32, k0 = (b2 >> 5) * 32;
        const int r = tid >> 3, c4 = (tid & 7) * 4;
        float4 v = *reinterpret_cast<const float4*>(&W1[(size_t)(k0 + r) * 1024 + n0 + c4]);
        tile[r][c4 + 0] = v.x; tile[r][c4 + 1] = v.y;
        tile[r][c4 + 2] = v.z; tile[r][c4 + 3] = v.w;
        __syncthreads();
        h4_t o;
        o[0] = (_Float16)tile[c4 + 0][r]; o[1] = (_Float16)tile[c4 + 1][r];
        o[2] = (_Float16)tile[c4 + 2][r]; o[3] = (_Float16)tile[c4 + 3][r];
        *reinterpret_cast<h4_t*>(&W1T[(size_t)(n0 + r) * 64 + k0 + c4]) = o;
    } else if (b < 3392) {                  // pack tail weights (K=32 B-frag)
        const int idx = (b - 1088) * 256 + tid;   // < 589824
        if (idx < 589824) {
            const int r = idx / 9216, qq = idx % 9216;
            float v;
            if (qq < 1024) {
                int nt = qq >> 8, rem = qq & 255, l = rem >> 2, j = rem & 3;
                int n = nt * 16 + (l & 15), k = (l >> 4) * 4 + j;
                v = a1W[(size_t)r * 1024 + k * 64 + n];
            } else if (qq < 5120) {
                int p = qq - 1024, kt = p >> 11, u = p & 2047, nt = u >> 9, s = u & 511,
                    l = s >> 3, j = s & 7;
                int n = nt * 16 + (l & 15), k = kt * 32 + (l >> 4) * 8 + j;
                v = a2W[(size_t)r * 4096 + k * 64 + n];
            } else {
                int p = qq - 5120, kt = p >> 11, u = p & 2047, nt = u >> 9, s = u & 511,
                    l = s >> 3, j = s & 7;
                int n = nt * 16 + (l & 15), k = kt * 32 + (l >> 4) * 8 + j;
                v = Wp2[((size_t)r * 64 + k) * 64 + n];
            }
            wpack[idx] = (_Float16)v;
        }
    } else {                                // split-K: t partials [8][4096][64]
        const int b2    = b - 3392;
        const int row0  = (b2 & 127) * 32;
        const int kbase = (b2 >> 7) * 128;
        const int r0    = (tid >> 4) * 2;
        const int c0    = (tid & 15) * 4;
        const int am    = tid >> 3;
        const int ak    = (tid & 7) * 4;
        float acc[2][4] = {};

#pragma unroll
        for (int kc = 0; kc < 128; kc += 32) {
            const int k0 = kbase + kc;
            float4 va = *reinterpret_cast<const float4*>(&x[(size_t)(row0 + am) * 1024 + k0 + ak]);
            As[ak + 0][am] = va.x; As[ak + 1][am] = va.y;
            As[ak + 2][am] = va.z; As[ak + 3][am] = va.w;
#pragma unroll
            for (int p = 0; p < 2; ++p) {
                int idx = tid + p * 256;
                int kk  = idx >> 4;
                int nq  = (idx & 15) * 4;
                *reinterpret_cast<float4*>(&Bs[kk][nq]) =
                    *reinterpret_cast<const float4*>(&Wpca[(size_t)(k0 + kk) * 64 + nq]);
            }
            __syncthreads();
#pragma unroll
            for (int k = 0; k < 32; ++k) {
                float a0 = As[k][r0], a1 = As[k][r0 + 1];
                float4 bv = *reinterpret_cast<const float4*>(&Bs[k][c0]);
                acc[0][0] = fmaf(a0, bv.x, acc[0][0]); acc[0][1] = fmaf(a0, bv.y, acc[0][1]);
                acc[0][2] = fmaf(a0, bv.z, acc[0][2]); acc[0][3] = fmaf(a0, bv.w, acc[0][3]);
                acc[1][0] = fmaf(a1, bv.x, acc[1][0]); acc[1][1] = fmaf(a1, bv.y, acc[1][1]);
                acc[1][2] = fmaf(a1, bv.z, acc[1][2]); acc[1][3] = fmaf(a1, bv.w, acc[1][3]);
            }
            __syncthreads();
        }
#pragma unroll
        for (int i = 0; i < 2; ++i) {
            float4 o; o.x = acc[i][0]; o.y = acc[i][1]; o.z = acc[i][2]; o.w = acc[i][3];
            *reinterpret_cast<float4*>(
                &P[((size_t)(b2 >> 7) * 4096 + row0 + r0 + i) * 64 + c0]) = o;
        }
    }
}

// ---------------------------------------------------------------------------
// K1b: t16 = fp16(sum_c P[c] + bias); ALSO inits out[row] = dot(bp2,Wl)+bl
// (constant term of the final layer; tail then atomicAdds chunk contributions;
// re-written every call so graph replays stay correct).
// ---------------------------------------------------------------------------
__global__ __launch_bounds__(256) void combine_t16(const float* __restrict__ P,
                                                   const float* __restrict__ bias,
                                                   const float* __restrict__ bp2,
                                                   const float* __restrict__ Wl,
                                                   const float* __restrict__ bl,
                                                   _Float16* __restrict__ t16,
                                                   float* __restrict__ out)
{
    const int idx = blockIdx.x * 256 + threadIdx.x;
    float s = bias[idx & 63];
#pragma unroll
    for (int c = 0; c < 8; ++c)
        s += P[(size_t)c * 262144 + idx];
    t16[idx] = (_Float16)s;

    if (idx < 4096) {
        float cst = bl[0];
#pragma unroll
        for (int f = 0; f < 64; ++f)
            cst += bp2[f] * Wl[f];
        out[idx] = cst;
    }
}

// ---------------------------------------------------------------------------
// K2: h1[4096][1024] = leaky(t16 @ W1 + b1) via fp16 MFMA (K=64). (R11)
// ---------------------------------------------------------------------------
__global__ __launch_bounds__(256) void gemm_k64_mfma(const _Float16* __restrict__ A,
                                                     const _Float16* __restrict__ BT,
                                                     const float* __restrict__ bias,
                                                     _Float16* __restrict__ C)
{
    __shared__ alignas(16) _Float16 As[128 * 64];
    __shared__ alignas(16) _Float16 Bs[128 * 64];
    const int tid = threadIdx.x;
    const int l   = tid & 63;
    const int w   = tid >> 6;
    const int wm  = w >> 1;
    const int wn  = w & 1;
    const int bm0 = blockIdx.y * 128;
    const int bn0 = blockIdx.x * 128;
    const int fr  = l & 15;
    const int fg  = l >> 4;
    const int srow  = l >> 3;
    const int sslot = l & 7;

#pragma unroll
    for (int i = 0; i < 4; ++i) {
        const int r0   = w * 32 + i * 8;
        const int rowA = r0 + srow;
        const int slot = sslot ^ (rowA & 7);
        __builtin_amdgcn_global_load_lds(
            (const __attribute__((address_space(1))) void*)&A[(size_t)(bm0 + rowA) * 64 + slot * 8],
            (__attribute__((address_space(3))) void*)&As[r0 * 64], 16, 0, 0);
        __builtin_amdgcn_global_load_lds(
            (const __attribute__((address_space(1))) void*)&BT[(size_t)(bn0 + rowA) * 64 + slot * 8],
            (__attribute__((address_space(3))) void*)&Bs[r0 * 64], 16, 0, 0);
    }
    __syncthreads();

    f32x4 acc[4][4] = {};
#pragma unroll
    for (int ks = 0; ks < 2; ++ks) {
        h8_t af[4], bf[4];
#pragma unroll
        for (int mt = 0; mt < 4; ++mt) {
            int row = wm * 64 + mt * 16 + fr;
            int sg  = ks * 4 + fg;
            af[mt] = *reinterpret_cast<const h8_t*>(&As[row * 64 + ((sg ^ (row & 7)) << 3)]);
        }
#pragma unroll
        for (int nt = 0; nt < 4; ++nt) {
            int row = wn * 64 + nt * 16 + fr;
            int sg  = ks * 4 + fg;
            bf[nt] = *reinterpret_cast<const h8_t*>(&Bs[row * 64 + ((sg ^ (row & 7)) << 3)]);
        }
#pragma unroll
        for (int mt = 0; mt < 4; ++mt)
#pragma unroll
            for (int nt = 0; nt < 4; ++nt)
                acc[mt][nt] = __builtin_amdgcn_mfma_f32_16x16x32_f16(af[mt], bf[nt],
                                                                     acc[mt][nt], 0, 0, 0);
    }

#pragma unroll
    for (int nt = 0; nt < 4; ++nt) {
        const int col = bn0 + wn * 64 + nt * 16 + fr;
        const float bv = bias[col];
#pragma unroll
        for (int mt = 0; mt < 4; ++mt)
#pragma unroll
            for (int rg = 0; rg < 4; ++rg) {
                const int row = bm0 + wm * 64 + mt * 16 + fg * 4 + rg;
                float v = acc[mt][nt][rg] + bv;
                C[(size_t)row * 1024 + col] = (_Float16)fmaxf(v, NEG_SLOPE * v);
            }
    }
}

// ---------------------------------------------------------------------------
// K3 v2: h2t = pack(leaky(h1 @ W2 + b2)). (R11)
// ---------------------------------------------------------------------------
__global__ __launch_bounds__(256) void gemm_mfma_f16_v2(const _Float16* __restrict__ A,
                                                        const _Float16* __restrict__ BT,
                                                        const float* __restrict__ bias,
                                                        _Float16* __restrict__ h2t)
{
    __shared__ alignas(16) _Float16 As[64 * 64];
    __shared__ alignas(16) _Float16 Bs[128 * 64];
    const int tid = threadIdx.x;
    const int l   = tid & 63;
    const int w   = tid >> 6;
    const int wm  = w >> 1;
    const int wn  = w & 1;
    const int bm0 = blockIdx.y * 64;
    const int bn0 = blockIdx.x * 128;
    const int fr  = l & 15;
    const int fg  = l >> 4;
    const int srow  = l >> 3;
    const int sslot = l & 7;

    f32x4 acc[2][4] = {};

    for (int k0 = 0; k0 < 1024; k0 += 64) {
#pragma unroll
        for (int i = 0; i < 2; ++i) {
            const int r0   = w * 16 + i * 8;
            const int rowA = r0 + srow;
            const int slot = sslot ^ (rowA & 7);
            __builtin_amdgcn_global_load_lds(
                (const __attribute__((address_space(1))) void*)&A[(size_t)(bm0 + rowA) * 1024 + k0 + slot * 8],
                (__attribute__((address_space(3))) void*)&As[r0 * 64], 16, 0, 0);
        }
#pragma unroll
        for (int i = 0; i < 4; ++i) {
            const int r0   = w * 32 + i * 8;
            const int rowB = r0 + srow;
            const int slot = sslot ^ (rowB & 7);
            __builtin_amdgcn_global_load_lds(
                (const __attribute__((address_space(1))) void*)&BT[(size_t)(bn0 + rowB) * 1024 + k0 + slot * 8],
                (__attribute__((address_space(3))) void*)&Bs[r0 * 64], 16, 0, 0);
        }
        __syncthreads();

#pragma unroll
        for (int ks = 0; ks < 2; ++ks) {
            h8_t af[2], bf[4];
#pragma unroll
            for (int mt = 0; mt < 2; ++mt) {
                int row = wm * 32 + mt * 16 + fr;
                int sg  = ks * 4 + fg;
                af[mt] = *reinterpret_cast<const h8_t*>(&As[row * 64 + ((sg ^ (row & 7)) << 3)]);
            }
#pragma unroll
            for (int nt = 0; nt < 4; ++nt) {
                int row = wn * 64 + nt * 16 + fr;
                int sg  = ks * 4 + fg;
                bf[nt] = *reinterpret_cast<const h8_t*>(&Bs[row * 64 + ((sg ^ (row & 7)) << 3)]);
            }
#pragma unroll
            for (int mt = 0; mt < 2; ++mt)
#pragma unroll
                for (int nt = 0; nt < 4; ++nt)
                    acc[mt][nt] = __builtin_amdgcn_mfma_f32_16x16x32_f16(af[mt], bf[nt],
                                                                         acc[mt][nt], 0, 0, 0);
        }
        __syncthreads();
    }

    const int rblk0 = (bm0 >> 4) + wm * 2;
    const int cblk0 = (bn0 >> 4) + wn * 4;
#pragma unroll
    for (int nt = 0; nt < 4; ++nt) {
        const int col = bn0 + wn * 64 + nt * 16 + fr;
        const float bv = bias[col];
#pragma unroll
        for (int mt = 0; mt < 2; ++mt) {
            h4_t pk;
#pragma unroll
            for (int r = 0; r < 4; ++r) {
                float v = acc[mt][nt][r] + bv;
                pk[r] = (_Float16)fmaxf(v, NEG_SLOPE * v);
            }
            *reinterpret_cast<h4_t*>(
                &h2t[(((size_t)(cblk0 + nt) * 256 + rblk0 + mt) * 16 + fr) * 16 + fg * 4]) = pk;
        }
    }
}

// ---------------------------------------------------------------------------
// K4: fused additive chain v5b — t2 chunk contribution collapsed to per-row
// scalar via Wl dot (linearity) + device-scope atomicAdd into out.
// No partials buffer, no reduce kernel. Compute core identical to R11 v5.
// ---------------------------------------------------------------------------
#define RCH 4

__global__ __launch_bounds__(256) void fused_tail5b(const _Float16* __restrict__ h2t,
                                                    const _Float16* __restrict__ wpack,
                                                    const float* __restrict__ a1b,
                                                    const float* __restrict__ a1bias,
                                                    const float* __restrict__ a2b,
                                                    const float* __restrict__ a2bias,
                                                    const float* __restrict__ Wl,
                                                    float* __restrict__ out)
{
    __shared__ alignas(16) _Float16 stage[2][11264];  // 2 x 22KB
    __shared__ alignas(16) _Float16 act[4][2048];     // per-wave, 2 tiles (16KB)

    const int tid = threadIdx.x;
    const int l = tid & 63, w = tid >> 6;
    const int c = l & 15, q = l >> 4;
    const int row0  = blockIdx.x * 128;
    const int rbase = blockIdx.y * RCH;
    const float b1s = a1bias[0], b2s = a2bias[0];

    const unsigned trl   = l * 8;
    const unsigned abase = lds_off(&act[w][0]);

    float b1v[RCH][4], b2v[RCH][4];
#pragma unroll
    for (int rl = 0; rl < RCH; ++rl)
#pragma unroll
        for (int nt = 0; nt < 4; ++nt) {
            b1v[rl][nt] = a1b[(rbase + rl) * 64 + nt * 16 + c] + b1s;
            b2v[rl][nt] = a2b[(rbase + rl) * 64 + nt * 16 + c] + b2s;
        }
    float wlv[4];
#pragma unroll
    for (int nt = 0; nt < 4; ++nt) wlv[nt] = Wl[nt * 16 + c];

    auto STAGE = [&](int rl, int b) {
        const int r = rbase + rl;
        const _Float16* hsrc = h2t + ((size_t)r * 256 + blockIdx.x * 8) * 256;
        const _Float16* wsrc = wpack + (size_t)r * 9216;
#pragma unroll
        for (int i = 0; i < 6; ++i) {
            const int ch = i * 4 + w;
            if (ch < 22) {
                const _Float16* src = (ch < 4) ? (hsrc + ch * 512) : (wsrc + (ch - 4) * 512);
                __builtin_amdgcn_global_load_lds(
                    (const __attribute__((address_space(1))) void*)(src + l * 8),
                    (__attribute__((address_space(3))) void*)&stage[b][ch * 512], 16, 0, 0);
            }
        }
    };

    STAGE(0, 0);
    __syncthreads();

    f32x4 accT[2][4] = {};
    int cur = 0;

#pragma unroll
    for (int rl = 0; rl < RCH; ++rl) {
        if (rl + 1 < RCH) STAGE(rl + 1, cur ^ 1);

        const _Float16* sp = &stage[cur][0];
        const unsigned sbytes = lds_off(sp);

        // ---- phase A: a[j] = leaky(h_tile[j] @ W1r + bias)
        h4_t ha0 = tr16(sbytes + (unsigned)(w) * 512 + trl);
        h4_t ha1 = tr16(sbytes + (unsigned)(w + 4) * 512 + trl);
        lgkm0();
        f32x4 pa[2][4];
#pragma unroll
        for (int nt = 0; nt < 4; ++nt) {
            h4_t bf = *reinterpret_cast<const h4_t*>(&sp[2048 + nt * 256 + l * 4]);
            pa[0][nt] = __builtin_amdgcn_mfma_f32_16x16x16f16(ha0, bf, (f32x4){0.f,0.f,0.f,0.f}, 0, 0, 0);
            pa[1][nt] = __builtin_amdgcn_mfma_f32_16x16x16f16(ha1, bf, (f32x4){0.f,0.f,0.f,0.f}, 0, 0, 0);
        }
#pragma unroll
        for (int j = 0; j < 2; ++j)
#pragma unroll
            for (int nt = 0; nt < 4; ++nt) {
                h4_t pk;
#pragma unroll
                for (int rg = 0; rg < 4; ++rg) {
                    float v = pa[j][nt][rg] + b1v[rl][nt];
                    pk[rg] = (_Float16)fmaxf(v, NEG_SLOPE * v);
                }
                const int kk = nt * 16 + c;
                const int hh = (kk >> 2) & 1;
                const int kp = (kk & 3) | ((kk >> 3) << 2);
                *reinterpret_cast<h4_t*>(&act[w][j * 1024 + hh * 512 + kp * 16 + q * 4]) = pk;
            }
        lgkm0();

        // ---- phase B: a2[j] = leaky(a[j] @ W2r + bias)
        h8_t afB[2][2];
#pragma unroll
        for (int j = 0; j < 2; ++j)
#pragma unroll
            for (int kt = 0; kt < 2; ++kt) {
                h4_t lo = tr16(abase + (unsigned)(j * 2048 + kt * 512) + trl);
                h4_t hi = tr16(abase + (unsigned)(j * 2048 + 1024 + kt * 512) + trl);
                afB[j][kt] = __builtin_shufflevector(lo, hi, 0, 1, 2, 3, 4, 5, 6, 7);
            }
        lgkm0();
        f32x4 pb[2][4] = {};
#pragma unroll
        for (int kt = 0; kt < 2; ++kt)
#pragma unroll
            for (int nt = 0; nt < 4; ++nt) {
                h8_t bf = *reinterpret_cast<const h8_t*>(&sp[3072 + kt * 2048 + nt * 512 + l * 8]);
                pb[0][nt] = __builtin_amdgcn_mfma_f32_16x16x32_f16(afB[0][kt], bf, pb[0][nt], 0, 0, 0);
                pb[1][nt] = __builtin_amdgcn_mfma_f32_16x16x32_f16(afB[1][kt], bf, pb[1][nt], 0, 0, 0);
            }
#pragma unroll
        for (int j = 0; j < 2; ++j)
#pragma unroll
            for (int nt = 0; nt < 4; ++nt) {
                h4_t pk;
#pragma unroll
                for (int rg = 0; rg < 4; ++rg) {
                    float v = pb[j][nt][rg] + b2v[rl][nt];
                    pk[rg] = (_Float16)fmaxf(v, NEG_SLOPE * v);
                }
                const int kk = nt * 16 + c;
                const int hh = (kk >> 2) & 1;
                const int kp = (kk & 3) | ((kk >> 3) << 2);
                *reinterpret_cast<h4_t*>(&act[w][j * 1024 + hh * 512 + kp * 16 + q * 4]) = pk;
            }
        lgkm0();

        // ---- phase C: t2[j] += a2[j] @ WpR
        h8_t afC[2][2];
#pragma unroll
        for (int j = 0; j < 2; ++j)
#pragma unroll
            for (int kt = 0; kt < 2; ++kt) {
                h4_t lo = tr16(abase + (unsigned)(j * 2048 + kt * 512) + trl);
                h4_t hi = tr16(abase + (unsigned)(j * 2048 + 1024 + kt * 512) + trl);
                afC[j][kt] = __builtin_shufflevector(lo, hi, 0, 1, 2, 3, 4, 5, 6, 7);
            }
        lgkm0();
#pragma unroll
        for (int kt = 0; kt < 2; ++kt)
#pragma unroll
            for (int nt = 0; nt < 4; ++nt) {
                h8_t bf = *reinterpret_cast<const h8_t*>(&sp[7168 + kt * 2048 + nt * 512 + l * 8]);
                accT[0][nt] = __builtin_amdgcn_mfma_f32_16x16x32_f16(afC[0][kt], bf, accT[0][nt], 0, 0, 0);
                accT[1][nt] = __builtin_amdgcn_mfma_f32_16x16x32_f16(afC[1][kt], bf, accT[1][nt], 0, 0, 0);
            }

        __syncthreads();
        cur ^= 1;
    }

    // ---- epilogue: per-row dot with Wl, reduce over the 16 c-lanes, atomicAdd
#pragma unroll
    for (int j = 0; j < 2; ++j)
#pragma unroll
        for (int rg = 0; rg < 4; ++rg) {
            float s = accT[j][0][rg] * wlv[0] + accT[j][1][rg] * wlv[1] +
                      accT[j][2][rg] * wlv[2] + accT[j][3][rg] * wlv[3];
            s += __shfl_xor(s, 1);
            s += __shfl_xor(s, 2);
            s += __shfl_xor(s, 4);
            s += __shfl_xor(s, 8);
            if (c == 0) {
                const int row = row0 + (w + 4 * j) * 16 + q * 4 + rg;
                atomicAdd(&out[row], s);
            }
        }
}

// ---------------------------------------------------------------------------
extern "C" void kernel_launch(void* const* d_in, const int* in_sizes, int n_in,
                              void* d_out, int out_size, void* d_ws, size_t ws_size,
                              hipStream_t stream)
{
    const float* x      = (const float*)d_in[0];
    const float* Wpca   = (const float*)d_in[1];
    const float* bpca   = (const float*)d_in[2];
    const float* W1     = (const float*)d_in[3];
    const float* b1     = (const float*)d_in[4];
    const float* W2     = (const float*)d_in[5];
    const float* b2     = (const float*)d_in[6];
    const float* a1W    = (const float*)d_in[7];
    const float* a1b    = (const float*)d_in[8];
    const float* a1bias = (const float*)d_in[9];
    const float* a2W    = (const float*)d_in[10];
    const float* a2b    = (const float*)d_in[11];
    const float* a2bias = (const float*)d_in[12];
    const float* Wp2    = (const float*)d_in[13];
    const float* bp2    = (const float*)d_in[14];
    const float* Wl     = (const float*)d_in[15];
    const float* bl     = (const float*)d_in[16];
    float* out = (float*)d_out;

    // workspace layout (bytes) — verified non-overlapping:
    //   t16 [0,0.5M)  h1h [1M,9M)  h2t [9M,17M)  W2T [17M,19M)
    //   wpack [19M,20.13M)  W1T [21M,21.13M)   tpart aliases h2t (dead then)
    char* wsb = (char*)d_ws;
    _Float16* t16   = (_Float16*)(wsb);
    _Float16* h1h   = (_Float16*)(wsb + (1ull  << 20));
    _Float16* h2t   = (_Float16*)(wsb + (9ull  << 20));
    _Float16* W2T   = (_Float16*)(wsb + (17ull << 20));
    _Float16* wpack = (_Float16*)(wsb + (19ull << 20));
    _Float16* W1T   = (_Float16*)(wsb + (21ull << 20));
    float*    tpart = (float*)   (wsb + (9ull  << 20));   // aliases h2t (dead then)

    // K0: prep (W2T+W1T+wpack) || split-K t-partials, one launch
    prep_and_splitk<<<dim3(4416), 256, 0, stream>>>(W2, W1, a1W, a2W, Wp2, x, Wpca,
                                                    W2T, W1T, wpack, tpart);
    // K1b: combine t partials -> fp16; also init out with const term
    combine_t16<<<dim3(1024), 256, 0, stream>>>(tpart, bpca, bp2, Wl, bl, t16, out);
    // K2: h1 = leaky(t @ W1 + b1) via MFMA (K=64)
    gemm_k64_mfma<<<dim3(8, 32), 256, 0, stream>>>(t16, W1T, b1, h1h);
    // K3: h2 (packed) = leaky(h1 @ W2 + b2) via MFMA
    gemm_mfma_f16_v2<<<dim3(8, 64), 256, 0, stream>>>(h1h, W2T, b2, h2t);
    // K4: fused additive chain -> atomicAdd chunk dots into out (no reduce kernel)
    fused_tail5b<<<dim3(32, 16), 256, 0, stream>>>(h2t, wpack, a1b, a1bias,
                                                   a2b, a2bias, Wl, out);
}